// Round 7
// baseline (297.617 us; speedup 1.0000x reference)
//
#include <hip/hip_runtime.h>
#include <hip/hip_bf16.h>
#include <math.h>

#define B_CONST 256
#define T_CONST 8192
#define P_CONST 16
#define H_CONST 1024

typedef __bf16 bf16x8 __attribute__((ext_vector_type(8)));
typedef __bf16 bf16x4 __attribute__((ext_vector_type(4)));
typedef float  f32x4  __attribute__((ext_vector_type(4)));

typedef __attribute__((address_space(3))) void       as3_void;
typedef const __attribute__((address_space(1))) void as1_cvoid;

__device__ __forceinline__ void gload_lds16(const void* g, void* l) {
    __builtin_amdgcn_global_load_lds((as1_cvoid*)g, (as3_void*)l, 16, 0, 0);
}

#define FENCE() asm volatile("" ::: "memory")

// fast gelu: x * sigmoid(1.5957691 * x * (1 + 0.044715 x^2))
__device__ __forceinline__ float gelu_fast(float x) {
    float z = 1.5957691216057308f * x * __builtin_fmaf(0.044715f, x * x, 1.0f);
    return x * __builtin_amdgcn_rcpf(1.0f + __expf(-z));
}

// ---------------- kernel 1: per-batch valid count (sum of mask) ----------------
__global__ void k_valid(const float* __restrict__ x, int* __restrict__ valid) {
    int b = blockIdx.x;
    const float* row = x + (size_t)b * (T_CONST * 2);
    float s = 0.f;
    for (int t = threadIdx.x; t < T_CONST; t += blockDim.x)
        s += row[2 * t + 1];
    __shared__ float red[256];
    red[threadIdx.x] = s;
    __syncthreads();
    for (int off = 128; off > 0; off >>= 1) {
        if (threadIdx.x < off) red[threadIdx.x] += red[threadIdx.x + off];
        __syncthreads();
    }
    if (threadIdx.x == 0) valid[b] = (int)(red[0] + 0.5f);
}

// ---------------- kernel 2: pc + scan; writes pc (as float) to out tail --------
__global__ void k_scan(const int* __restrict__ valid, int* __restrict__ pc,
                       int* __restrict__ starts, int* __restrict__ cum,
                       float* __restrict__ out_pc) {
    __shared__ int s[B_CONST];
    int t = threadIdx.x;
    int v = valid[t];
    int p = (v + P_CONST - 1) / P_CONST;
    s[t] = p;
    __syncthreads();
    for (int off = 1; off < B_CONST; off <<= 1) {
        int add = (t >= off) ? s[t - off] : 0;
        __syncthreads();
        s[t] += add;
        __syncthreads();
    }
    pc[t] = p;
    cum[t] = s[t];
    starts[t] = s[t] - p;
    out_pc[t] = (float)p;
}

// ---------------- kernel 3: gather patches (total x 32 bf16, K padded) ---------
__global__ void k_gather(const float* __restrict__ x, const int* __restrict__ valid,
                         const int* __restrict__ cum, const int* __restrict__ starts,
                         __bf16* __restrict__ patches, int total) {
    int tid = blockIdx.x * blockDim.x + threadIdx.x;
    if (tid >= total * 32) return;
    int j = tid >> 5, k = tid & 31;
    int lo = 0, hi = B_CONST - 1;
    while (lo < hi) { int mid = (lo + hi) >> 1; if (cum[mid] > j) hi = mid; else lo = mid + 1; }
    int b = lo;
    int p = j - starts[b];
    float v = 0.f;
    if (k < 16) {
        int idx = p * P_CONST + k;
        if (idx < valid[b]) v = x[(size_t)b * (T_CONST * 2) + 2 * idx];
    }
    patches[tid] = (__bf16)v;
}

// ---------------- weight prep: transpose K x N fp32 -> N x K bf16 --------------
__global__ void k_transpose_cvt(const float* __restrict__ W, __bf16* __restrict__ WT,
                                int Kdim, int Ndim) {
    __shared__ float tile[32][33];
    int n0 = blockIdx.x * 32, k0 = blockIdx.y * 32;
    int c = threadIdx.x & 31, r0 = threadIdx.x >> 5;
    for (int r = r0; r < 32; r += 8) tile[r][c] = W[(size_t)(k0 + r) * Ndim + n0 + c];
    __syncthreads();
    for (int r = r0; r < 32; r += 8) WT[(size_t)(n0 + r) * Kdim + k0 + c] = (__bf16)tile[c][r];
}

// w1 is 16 x 1024 -> w1t 1024 x 32 (zero-padded K)
__global__ void k_w1t(const float* __restrict__ w1, __bf16* __restrict__ w1t) {
    int n = blockIdx.x * 256 + threadIdx.x;
    if (n >= H_CONST) return;
    for (int k = 0; k < 32; ++k)
        w1t[n * 32 + k] = (k < 16) ? (__bf16)w1[k * H_CONST + n] : (__bf16)0.f;
}

// ---------------- layer-1 GEMM (K=32): proven R3 128x128 structure -------------
template <bool GELU, typename TOut>
__global__ __launch_bounds__(256) void k_mfma_gemm(
    const __bf16* __restrict__ A, const __bf16* __restrict__ WT,
    const float* __restrict__ bias, TOut* __restrict__ C,
    int M, int N, int K) {
    __shared__ __bf16 As[128][32];
    __shared__ __bf16 Bs[128][32];

    const int lane = threadIdx.x & 63;
    const int wid  = threadIdx.x >> 6;
    const int wr = wid >> 1, wc = wid & 1;

    const int nwg_x = gridDim.x;
    const int orig = blockIdx.y * nwg_x + blockIdx.x;
    const int cpx = (nwg_x * gridDim.y) >> 3;
    const int wgid = (orig & 7) * cpx + (orig >> 3);
    const int brow = (wgid / nwg_x) * 128;
    const int bcol = (wgid % nwg_x) * 128;

    f32x4 acc[4][4];
#pragma unroll
    for (int i = 0; i < 4; ++i)
#pragma unroll
        for (int j = 0; j < 4; ++j)
            acc[i][j] = (f32x4){0.f, 0.f, 0.f, 0.f};

    const int sr = lane >> 2;
    const int sc = (lane & 3) * 8;
    const size_t a_base = (size_t)(brow + wid * 16 + sr) * K + sc;
    const size_t b_base = (size_t)(bcol + wid * 16 + sr) * K + sc;
    const size_t stride64 = (size_t)64 * K;

    const int lr = lane & 15;
    const int lk = (lane >> 4) * 8;

    for (int kt = 0; kt < K; kt += 32) {
        gload_lds16(A  + a_base + kt,            &As[wid * 16][0]);
        gload_lds16(A  + a_base + stride64 + kt, &As[64 + wid * 16][0]);
        gload_lds16(WT + b_base + kt,            &Bs[wid * 16][0]);
        gload_lds16(WT + b_base + stride64 + kt, &Bs[64 + wid * 16][0]);
        __syncthreads();

        bf16x8 af[4], bfr[4];
#pragma unroll
        for (int mf = 0; mf < 4; ++mf)
            af[mf] = *(const bf16x8*)&As[wr * 64 + mf * 16 + lr][lk];
#pragma unroll
        for (int nf = 0; nf < 4; ++nf)
            bfr[nf] = *(const bf16x8*)&Bs[wc * 64 + nf * 16 + lr][lk];
#pragma unroll
        for (int mf = 0; mf < 4; ++mf)
#pragma unroll
            for (int nf = 0; nf < 4; ++nf)
                acc[mf][nf] = __builtin_amdgcn_mfma_f32_16x16x32_bf16(
                    bfr[nf], af[mf], acc[mf][nf], 0, 0, 0);
        __syncthreads();
    }

    const int m_off = lane & 15;
    const int c4 = (lane >> 4) << 2;
#pragma unroll
    for (int nf = 0; nf < 4; ++nf) {
        const int col0 = bcol + wc * 64 + nf * 16 + c4;
        const f32x4 bv = *(const f32x4*)&bias[col0];
#pragma unroll
        for (int mf = 0; mf < 4; ++mf) {
            const int row = brow + wr * 64 + mf * 16 + m_off;
            f32x4 v = acc[mf][nf] + bv;
            if (GELU) {
#pragma unroll
                for (int r = 0; r < 4; ++r) v[r] = gelu_fast(v[r]);
            }
            if constexpr (sizeof(TOut) == 4) {
                *(f32x4*)&C[(size_t)row * N + col0] = v;
            } else {
                bf16x4 o;
#pragma unroll
                for (int r = 0; r < 4; ++r) o[r] = (__bf16)v[r];
                *(bf16x4*)&C[(size_t)row * N + col0] = o;
            }
        }
    }
}

// ---------------- big GEMM: 256x256 8-phase template (T3+T4+T2+T5) -------------
// BM=BN=256, BK=64, 8 waves (2M x 4N), per-wave 128x64 output.
// LDS 128 KiB: A,B each [2dbuf][2half][128][64] bf16.
// Per K-tile: 4 phases. Phase q reads A-frags mf {2q,2q+1} (+ all 8 B-frags at
// q0 -> B fully consumed first phase); stages one half-tile of the stream
// s(p)=p+7 (in-kt order B0,B1,A0,A1); counted vmcnt(6) at each kt's LAST phase
// before its barrier (the barrier publishes per-wave vmcnt block-wide);
// vmcnt(0) once at kt=NT-2. Wave mf->row map interleaved so A-h0 is consumed
// in q0/q1 and A-h1 in q2/q3 (makes every stage WAR-safe across the barriers).
// R4/R6-proven XOR swizzle: linear LDS dest + pre-swizzled global source +
// ^((row&7)<<4) on ds_read byte offset (measured 0 bank conflicts).
template <bool GELU, typename TOut>
__global__ __launch_bounds__(512, 2) void k_gemm_8p(
    const __bf16* __restrict__ A, const __bf16* __restrict__ WT,
    const float* __restrict__ bias, TOut* __restrict__ C,
    int Mstore, int N, int K) {
    __shared__ __bf16 As[2][2][128][64];   // 64 KiB
    __shared__ __bf16 Bs[2][2][128][64];   // 64 KiB

    const int tid  = threadIdx.x;
    const int lane = tid & 63;
    const int w    = tid >> 6;   // 0..7
    const int wr   = w >> 2;     // 0..1 (M dir)
    const int wc   = w & 3;      // 0..3 (N dir)

    // bijective XCD swizzle (nwg = 516: q=64, r=4)
    const int gx   = gridDim.x;
    const int nwg  = gx * gridDim.y;
    const int orig = blockIdx.y * gx + blockIdx.x;
    const int qq = nwg >> 3, rr = nwg & 7;
    const int xcd = orig & 7, bix = orig >> 3;
    const int wgid = (xcd < rr ? xcd * (qq + 1) : rr * (qq + 1) + (xcd - rr) * qq) + bix;
    const int brow = (wgid / gx) * 256;
    const int bcol = (wgid % gx) * 256;

    f32x4 acc[8][4];
#pragma unroll
    for (int i = 0; i < 8; ++i)
#pragma unroll
        for (int j = 0; j < 4; ++j)
            acc[i][j] = (f32x4){0.f, 0.f, 0.f, 0.f};

    // staging geometry: half-tile = 128 rows x 64 cols; 2 gload_lds per thread.
    // thread t covers row = i*64 + w*8 + (lane>>3), colgrp = lane&7;
    // global source pre-swizzled: fetch colgrp (lane&7)^((lane>>3)&7).
    const int srow  = w * 8 + (lane >> 3);                      // 0..63
    const int scolg = ((lane & 7) ^ ((lane >> 3) & 7)) << 3;    // elem offset

#define STG_HT(SRCP, RB, LB, KT)                                               \
    do {                                                                       \
        gload_lds16((SRCP) + (size_t)((RB) + srow) * K + (KT) * 64 + scolg,    \
                    (LB) + w * 1024);                                          \
        gload_lds16((SRCP) + (size_t)((RB) + 64 + srow) * K + (KT) * 64 + scolg,\
                    (LB) + w * 1024 + 8192);                                   \
    } while (0)

    const int NT = K >> 6;   // 16
    // prologue: kt0 {B0,B1,A0,A1}, kt1 {B0,B1,A0}  (7 half-tiles = 14 loads)
    STG_HT(WT, bcol,       (char*)&Bs[0][0][0][0], 0);
    STG_HT(WT, bcol + 128, (char*)&Bs[0][1][0][0], 0);
    STG_HT(A,  brow,       (char*)&As[0][0][0][0], 0);
    STG_HT(A,  brow + 128, (char*)&As[0][1][0][0], 0);
    STG_HT(WT, bcol,       (char*)&Bs[1][0][0][0], 1);
    STG_HT(WT, bcol + 128, (char*)&Bs[1][1][0][0], 1);
    STG_HT(A,  brow,       (char*)&As[1][0][0][0], 1);
    asm volatile("s_waitcnt vmcnt(6)" ::: "memory");   // kt0 landed; 3 half-tiles in flight
    FENCE();
    __builtin_amdgcn_s_barrier();
    FENCE();

    const int lr   = lane & 15;
    const int hi16 = (lane >> 4) * 16;
    const int rswz = (lane & 7) << 4;

    for (int kt = 0; kt < NT; ++kt) {
        const int db = kt & 1;
        const char* Ad = (const char*)&As[db][0][0][0];
        const char* Bd = (const char*)&Bs[db][0][0][0];
        bf16x8 bfr[4][2];
#pragma unroll
        for (int q = 0; q < 4; ++q) {
            if (q == 0) {
#pragma unroll
                for (int nf = 0; nf < 4; ++nf)
#pragma unroll
                    for (int kk = 0; kk < 2; ++kk)
                        bfr[nf][kk] = *(const bf16x8*)(Bd + (wc >> 1) * 16384 +
                            ((wc & 1) * 64 + nf * 16 + lr) * 128 +
                            ((kk * 64 + hi16) ^ rswz));
            }
            bf16x8 af[2][2];
#pragma unroll
            for (int j = 0; j < 2; ++j)
#pragma unroll
                for (int kk = 0; kk < 2; ++kk) {
                    const int mf = q * 2 + j;
                    af[j][kk] = *(const bf16x8*)(Ad + (mf >> 2) * 16384 +
                        ((mf & 3) * 16 + wr * 64 + lr) * 128 +
                        ((kk * 64 + hi16) ^ rswz));
                }
            // staging stream s(p)=p+7: q0 -> A-h1(kt+1, other dbuf);
            // q1 -> B-h0(kt+2, this dbuf); q2 -> B-h1(kt+2); q3 -> A-h0(kt+2)
            if (q == 0) {
                if (kt + 1 < NT)
                    STG_HT(A, brow + 128, (char*)&As[(kt + 1) & 1][1][0][0], kt + 1);
            } else if (q == 1) {
                if (kt + 2 < NT)
                    STG_HT(WT, bcol, (char*)&Bs[db][0][0][0], kt + 2);
            } else if (q == 2) {
                if (kt + 2 < NT)
                    STG_HT(WT, bcol + 128, (char*)&Bs[db][1][0][0], kt + 2);
            } else {
                if (kt + 2 < NT) {
                    STG_HT(A, brow, (char*)&As[db][0][0][0], kt + 2);
                    asm volatile("s_waitcnt vmcnt(6)" ::: "memory");  // kt+1 landed
                } else if (kt + 1 < NT) {
                    asm volatile("s_waitcnt vmcnt(0)" ::: "memory");  // tail drain
                }
            }
            FENCE();
            __builtin_amdgcn_s_barrier();
            FENCE();
            __builtin_amdgcn_s_setprio(1);
#pragma unroll
            for (int kk = 0; kk < 2; ++kk)
#pragma unroll
                for (int j = 0; j < 2; ++j)
#pragma unroll
                    for (int nf = 0; nf < 4; ++nf)
                        acc[q * 2 + j][nf] = __builtin_amdgcn_mfma_f32_16x16x32_bf16(
                            bfr[nf][kk], af[j][kk], acc[q * 2 + j][nf], 0, 0, 0);
            __builtin_amdgcn_s_setprio(0);
            FENCE();
            __builtin_amdgcn_s_barrier();
            FENCE();
        }
    }
#undef STG_HT

    // epilogue: swapped C^T frag -> lane holds 4 consecutive cols of one row.
    // mf -> global row: (mf&3)*16 + wr*64 + (mf>>2)*128 (interleaved halves).
    const int c4 = (lane >> 4) << 2;
#pragma unroll
    for (int nf = 0; nf < 4; ++nf) {
        const int col0 = bcol + wc * 64 + nf * 16 + c4;
        const f32x4 bv = *(const f32x4*)&bias[col0];
#pragma unroll
        for (int mf = 0; mf < 8; ++mf) {
            const int row = brow + (mf & 3) * 16 + wr * 64 + (mf >> 2) * 128 + lr;
            if (row < Mstore) {
                f32x4 v = acc[mf][nf] + bv;
                if (GELU) {
#pragma unroll
                    for (int rr = 0; rr < 4; ++rr) v[rr] = gelu_fast(v[rr]);
                }
                if constexpr (sizeof(TOut) == 4) {
                    *(f32x4*)&C[(size_t)row * N + col0] = v;
                } else {
                    bf16x4 o;
#pragma unroll
                    for (int rr = 0; rr < 4; ++rr) o[rr] = (__bf16)v[rr];
                    *(bf16x4*)&C[(size_t)row * N + col0] = o;
                }
            }
        }
    }
}

extern "C" void kernel_launch(void* const* d_in, const int* in_sizes, int n_in,
                              void* d_out, int out_size, void* d_ws, size_t ws_size,
                              hipStream_t stream) {
    const float* x  = (const float*)d_in[0];
    const float* w1 = (const float*)d_in[1];
    const float* b1 = (const float*)d_in[2];
    const float* w2 = (const float*)d_in[3];
    const float* b2 = (const float*)d_in[4];
    const float* w3 = (const float*)d_in[5];
    const float* b3 = (const float*)d_in[6];

    const int total = (out_size - B_CONST) / H_CONST;  // 32896
    const int MPAD  = ((total + 255) / 256) * 256;     // 33024
    float* out = (float*)d_out;
    float* out_pc = out + (size_t)total * H_CONST;

    char* ws = (char*)d_ws;
    int* valid  = (int*)ws;
    int* pc     = valid + 256;
    int* starts = pc + 256;
    int* cum    = starts + 256;
    __bf16* w1t = (__bf16*)(ws + 4096);                        // 1024x32
    __bf16* w2t = w1t + (size_t)H_CONST * 32;                  // 1024x1024
    __bf16* w3t = w2t + (size_t)H_CONST * H_CONST;             // 1024x1024
    __bf16* patches = w3t + (size_t)H_CONST * H_CONST;         // total x 32
    __bf16* h1 = patches + (size_t)total * 32;                 // MPAD x 1024
    __bf16* h2 = h1 + (size_t)MPAD * H_CONST;                  // MPAD x 1024

    k_valid<<<B_CONST, 256, 0, stream>>>(x, valid);
    k_scan<<<1, B_CONST, 0, stream>>>(valid, pc, starts, cum, out_pc);
    k_gather<<<(total * 32 + 255) / 256, 256, 0, stream>>>(x, valid, cum, starts, patches, total);
    k_w1t<<<4, 256, 0, stream>>>(w1, w1t);
    dim3 tg(H_CONST / 32, H_CONST / 32);
    k_transpose_cvt<<<tg, 256, 0, stream>>>(w2, w2t, H_CONST, H_CONST);
    k_transpose_cvt<<<tg, 256, 0, stream>>>(w3, w3t, H_CONST, H_CONST);

    // layer 1: K=32 (R3 kernel, M=32896 = 257*128)
    dim3 g1(H_CONST / 128, total / 128);   // 8 x 257 = 2056, %8 == 0
    k_mfma_gemm<true, __bf16><<<g1, dim3(256), 0, stream>>>(patches, w1t, b1, h1, total, H_CONST, 32);

    // layers 2/3: 256x256 8-phase template, M padded to 33024 = 129*256
    dim3 g8(H_CONST / 256, MPAD / 256);    // 4 x 129 = 516 blocks
    k_gemm_8p<true,  __bf16><<<g8, dim3(512), 0, stream>>>(h1, w2t, b2, h2, MPAD, H_CONST, H_CONST);
    k_gemm_8p<false, float ><<<g8, dim3(512), 0, stream>>>(h2, w3t, b3, out, total, H_CONST, H_CONST);
}

// Round 8
// 250.540 us; speedup vs baseline: 1.1879x; 1.1879x over previous
//
#include <hip/hip_runtime.h>
#include <hip/hip_bf16.h>
#include <math.h>

#define B_CONST 256
#define T_CONST 8192
#define P_CONST 16
#define H_CONST 1024

typedef __bf16 bf16x8 __attribute__((ext_vector_type(8)));
typedef __bf16 bf16x4 __attribute__((ext_vector_type(4)));
typedef float  f32x4  __attribute__((ext_vector_type(4)));

typedef __attribute__((address_space(3))) void       as3_void;
typedef const __attribute__((address_space(1))) void as1_cvoid;

__device__ __forceinline__ void gload_lds16(const void* g, void* l) {
    __builtin_amdgcn_global_load_lds((as1_cvoid*)g, (as3_void*)l, 16, 0, 0);
}

#define FENCE() asm volatile("" ::: "memory")

// fast gelu: x * sigmoid(1.5957691 * x * (1 + 0.044715 x^2))
__device__ __forceinline__ float gelu_fast(float x) {
    float z = 1.5957691216057308f * x * __builtin_fmaf(0.044715f, x * x, 1.0f);
    return x * __builtin_amdgcn_rcpf(1.0f + __expf(-z));
}

// ---------------- kernel 1: per-batch valid count (sum of mask) ----------------
__global__ void k_valid(const float* __restrict__ x, int* __restrict__ valid) {
    int b = blockIdx.x;
    const float* row = x + (size_t)b * (T_CONST * 2);
    float s = 0.f;
    for (int t = threadIdx.x; t < T_CONST; t += blockDim.x)
        s += row[2 * t + 1];
    __shared__ float red[256];
    red[threadIdx.x] = s;
    __syncthreads();
    for (int off = 128; off > 0; off >>= 1) {
        if (threadIdx.x < off) red[threadIdx.x] += red[threadIdx.x + off];
        __syncthreads();
    }
    if (threadIdx.x == 0) valid[b] = (int)(red[0] + 0.5f);
}

// ---------------- kernel 2: pc + scan; writes pc (as float) to out tail --------
__global__ void k_scan(const int* __restrict__ valid, int* __restrict__ pc,
                       int* __restrict__ starts, int* __restrict__ cum,
                       float* __restrict__ out_pc) {
    __shared__ int s[B_CONST];
    int t = threadIdx.x;
    int v = valid[t];
    int p = (v + P_CONST - 1) / P_CONST;
    s[t] = p;
    __syncthreads();
    for (int off = 1; off < B_CONST; off <<= 1) {
        int add = (t >= off) ? s[t - off] : 0;
        __syncthreads();
        s[t] += add;
        __syncthreads();
    }
    pc[t] = p;
    cum[t] = s[t];
    starts[t] = s[t] - p;
    out_pc[t] = (float)p;
}

// ---------------- kernel 3: gather patches (total x 32 bf16, K padded) ---------
__global__ void k_gather(const float* __restrict__ x, const int* __restrict__ valid,
                         const int* __restrict__ cum, const int* __restrict__ starts,
                         __bf16* __restrict__ patches, int total) {
    int tid = blockIdx.x * blockDim.x + threadIdx.x;
    if (tid >= total * 32) return;
    int j = tid >> 5, k = tid & 31;
    int lo = 0, hi = B_CONST - 1;
    while (lo < hi) { int mid = (lo + hi) >> 1; if (cum[mid] > j) hi = mid; else lo = mid + 1; }
    int b = lo;
    int p = j - starts[b];
    float v = 0.f;
    if (k < 16) {
        int idx = p * P_CONST + k;
        if (idx < valid[b]) v = x[(size_t)b * (T_CONST * 2) + 2 * idx];
    }
    patches[tid] = (__bf16)v;
}

// ---------------- weight prep: transpose K x N fp32 -> N x K bf16 --------------
__global__ void k_transpose_cvt(const float* __restrict__ W, __bf16* __restrict__ WT,
                                int Kdim, int Ndim) {
    __shared__ float tile[32][33];
    int n0 = blockIdx.x * 32, k0 = blockIdx.y * 32;
    int c = threadIdx.x & 31, r0 = threadIdx.x >> 5;
    for (int r = r0; r < 32; r += 8) tile[r][c] = W[(size_t)(k0 + r) * Ndim + n0 + c];
    __syncthreads();
    for (int r = r0; r < 32; r += 8) WT[(size_t)(n0 + r) * Kdim + k0 + c] = (__bf16)tile[c][r];
}

// w1 is 16 x 1024 -> w1t 1024 x 32 (zero-padded K)
__global__ void k_w1t(const float* __restrict__ w1, __bf16* __restrict__ w1t) {
    int n = blockIdx.x * 256 + threadIdx.x;
    if (n >= H_CONST) return;
    for (int k = 0; k < 32; ++k)
        w1t[n * 32 + k] = (k < 16) ? (__bf16)w1[k * H_CONST + n] : (__bf16)0.f;
}

// ---------------- layer-1 GEMM (K=32): proven R3 128x128 structure -------------
template <bool GELU, typename TOut>
__global__ __launch_bounds__(256) void k_mfma_gemm(
    const __bf16* __restrict__ A, const __bf16* __restrict__ WT,
    const float* __restrict__ bias, TOut* __restrict__ C,
    int M, int N, int K) {
    __shared__ __bf16 As[128][32];
    __shared__ __bf16 Bs[128][32];

    const int lane = threadIdx.x & 63;
    const int wid  = threadIdx.x >> 6;
    const int wr = wid >> 1, wc = wid & 1;

    const int nwg_x = gridDim.x;
    const int orig = blockIdx.y * nwg_x + blockIdx.x;
    const int cpx = (nwg_x * gridDim.y) >> 3;
    const int wgid = (orig & 7) * cpx + (orig >> 3);
    const int brow = (wgid / nwg_x) * 128;
    const int bcol = (wgid % nwg_x) * 128;

    f32x4 acc[4][4];
#pragma unroll
    for (int i = 0; i < 4; ++i)
#pragma unroll
        for (int j = 0; j < 4; ++j)
            acc[i][j] = (f32x4){0.f, 0.f, 0.f, 0.f};

    const int sr = lane >> 2;
    const int sc = (lane & 3) * 8;
    const size_t a_base = (size_t)(brow + wid * 16 + sr) * K + sc;
    const size_t b_base = (size_t)(bcol + wid * 16 + sr) * K + sc;
    const size_t stride64 = (size_t)64 * K;

    const int lr = lane & 15;
    const int lk = (lane >> 4) * 8;

    for (int kt = 0; kt < K; kt += 32) {
        gload_lds16(A  + a_base + kt,            &As[wid * 16][0]);
        gload_lds16(A  + a_base + stride64 + kt, &As[64 + wid * 16][0]);
        gload_lds16(WT + b_base + kt,            &Bs[wid * 16][0]);
        gload_lds16(WT + b_base + stride64 + kt, &Bs[64 + wid * 16][0]);
        __syncthreads();

        bf16x8 af[4], bfr[4];
#pragma unroll
        for (int mf = 0; mf < 4; ++mf)
            af[mf] = *(const bf16x8*)&As[wr * 64 + mf * 16 + lr][lk];
#pragma unroll
        for (int nf = 0; nf < 4; ++nf)
            bfr[nf] = *(const bf16x8*)&Bs[wc * 64 + nf * 16 + lr][lk];
#pragma unroll
        for (int mf = 0; mf < 4; ++mf)
#pragma unroll
            for (int nf = 0; nf < 4; ++nf)
                acc[mf][nf] = __builtin_amdgcn_mfma_f32_16x16x32_bf16(
                    bfr[nf], af[mf], acc[mf][nf], 0, 0, 0);
        __syncthreads();
    }

    const int m_off = lane & 15;
    const int c4 = (lane >> 4) << 2;
#pragma unroll
    for (int nf = 0; nf < 4; ++nf) {
        const int col0 = bcol + wc * 64 + nf * 16 + c4;
        const f32x4 bv = *(const f32x4*)&bias[col0];
#pragma unroll
        for (int mf = 0; mf < 4; ++mf) {
            const int row = brow + wr * 64 + mf * 16 + m_off;
            f32x4 v = acc[mf][nf] + bv;
            if (GELU) {
#pragma unroll
                for (int r = 0; r < 4; ++r) v[r] = gelu_fast(v[r]);
            }
            if constexpr (sizeof(TOut) == 4) {
                *(f32x4*)&C[(size_t)row * N + col0] = v;
            } else {
                bf16x4 o;
#pragma unroll
                for (int r = 0; r < 4; ++r) o[r] = (__bf16)v[r];
                *(bf16x4*)&C[(size_t)row * N + col0] = o;
            }
        }
    }
}

// ---------------- big GEMM: ring-3 BK=32, counted vmcnt, 1 barrier/tile --------
// R6 skeleton (128x128 tile, 4 waves 2x2, 3 blocks/CU) + T4 counted-vmcnt:
// LDS ring of 3 buffers (48 KiB total), staged 2 K-tiles ahead.
// Per K-tile t: { vmcnt(4) [tile-t's own 4 loads landed; t+1's 4 in flight]
//   -> s_barrier (publishes all waves' t-data; also guarantees buf[(t+2)%3]'s
//      readers (iteration t-1) are done) -> fence
//   -> STG(t+2) into buf[(t+2)%3]  (no reader until t+2: WAR-safe, no 2nd barrier)
//   -> 8 ds_read_b128 -> 16 MFMA }.
// vmcnt reaches 0 only at the last tile. Loads get ~2 tile-times to land.
// Swizzle for 64B rows (both-sides, rule 21): slot' = slot ^ ((row>>1)&3);
// per wave-read every 4-bank group receives exactly 8 chunks = conflict-free.
template <bool GELU, typename TOut>
__global__ __launch_bounds__(256, 3) void k_gemm_r3(
    const __bf16* __restrict__ A, const __bf16* __restrict__ WT,
    const float* __restrict__ bias, TOut* __restrict__ C,
    int M, int N, int K) {
    __shared__ __bf16 As[3][128][32];   // 24 KiB
    __shared__ __bf16 Bs[3][128][32];   // 24 KiB

    const int lane = threadIdx.x & 63;
    const int wid  = threadIdx.x >> 6;
    const int wr = wid >> 1, wc = wid & 1;

    const int nwg_x = gridDim.x;
    const int orig = blockIdx.y * nwg_x + blockIdx.x;
    const int cpx = (nwg_x * gridDim.y) >> 3;   // nwg = 2056, %8 == 0
    const int wgid = (orig & 7) * cpx + (orig >> 3);
    const int brow = (wgid / nwg_x) * 128;
    const int bcol = (wgid % nwg_x) * 128;

    f32x4 acc[4][4];
#pragma unroll
    for (int i = 0; i < 4; ++i)
#pragma unroll
        for (int j = 0; j < 4; ++j)
            acc[i][j] = (f32x4){0.f, 0.f, 0.f, 0.f};

    // staging: per K-tile each wave loads 16 rows of A (2 chunks) + 16 of B.
    // gload_lds dest = wave-uniform base + lane*16: lane l -> row base+ (l>>2),
    // slot l&3. Pre-swizzled global source: fetch col-group (l&3)^((l>>3)&3)
    // == (l&3)^(row>>1 & 3) for row = i*64 + 16w + (l>>2).
    const int srow = (lane >> 2);                    // 0..15 within chunk
    const int sgrp = ((lane & 3) ^ ((lane >> 3) & 3)) * 8;   // elem offset
    const __bf16* Ab0 = A  + (size_t)(brow + wid * 16 + srow) * K + sgrp;
    const __bf16* Bb0 = WT + (size_t)(bcol + wid * 16 + srow) * K + sgrp;
    const size_t r64 = (size_t)64 * K;

#define STG(buf, ko)                                              \
    do {                                                          \
        gload_lds16(Ab0 + (ko),       &As[buf][wid * 16][0]);     \
        gload_lds16(Ab0 + r64 + (ko), &As[buf][64 + wid * 16][0]);\
        gload_lds16(Bb0 + (ko),       &Bs[buf][wid * 16][0]);     \
        gload_lds16(Bb0 + r64 + (ko), &Bs[buf][64 + wid * 16][0]);\
    } while (0)

    // fragment-read addressing: row = {wr|wc}*64 + f*16 + lr, 16B slot
    // g = lane>>4 read at slot g ^ ((lr>>1)&3)  (row>>1 &3 == lr>>1 &3).
    const int lr  = lane & 15;
    const int g   = lane >> 4;
    const int cb  = (g ^ ((lr >> 1) & 3)) << 4;      // swizzled byte offset

    const int nt = K >> 5;   // 32 K-tiles
    STG(0, 0);
    STG(1, 32);

    for (int t = 0; t < nt; ++t) {
        if (t < nt - 1) { asm volatile("s_waitcnt vmcnt(4)" ::: "memory"); }
        else            { asm volatile("s_waitcnt vmcnt(0)" ::: "memory"); }
        __builtin_amdgcn_s_barrier();
        FENCE();

        const int cur = t % 3;
        if (t + 2 < nt) STG((t + 2) % 3, (t + 2) << 5);

        const char* ab = (const char*)&As[cur][0][0];
        const char* bb = (const char*)&Bs[cur][0][0];
        bf16x8 af[4], bfr[4];
#pragma unroll
        for (int mf = 0; mf < 4; ++mf)
            af[mf] = *(const bf16x8*)(ab + (wr * 64 + mf * 16 + lr) * 64 + cb);
#pragma unroll
        for (int nf = 0; nf < 4; ++nf)
            bfr[nf] = *(const bf16x8*)(bb + (wc * 64 + nf * 16 + lr) * 64 + cb);

        __builtin_amdgcn_s_setprio(1);
#pragma unroll
        for (int mf = 0; mf < 4; ++mf)
#pragma unroll
            for (int nf = 0; nf < 4; ++nf)
                acc[mf][nf] = __builtin_amdgcn_mfma_f32_16x16x32_bf16(
                    bfr[nf], af[mf], acc[mf][nf], 0, 0, 0);
        __builtin_amdgcn_s_setprio(0);
        FENCE();
    }
#undef STG

    // epilogue: swapped C^T frag -> lane holds 4 consecutive cols of one row
    const int c4 = (lane >> 4) << 2;
#pragma unroll
    for (int nf = 0; nf < 4; ++nf) {
        const int col0 = bcol + wc * 64 + nf * 16 + c4;
        const f32x4 bv = *(const f32x4*)&bias[col0];
#pragma unroll
        for (int mf = 0; mf < 4; ++mf) {
            const int row = brow + wr * 64 + mf * 16 + lr;
            f32x4 v = acc[mf][nf] + bv;
            if (GELU) {
#pragma unroll
                for (int rr = 0; rr < 4; ++rr) v[rr] = gelu_fast(v[rr]);
            }
            if constexpr (sizeof(TOut) == 4) {
                *(f32x4*)&C[(size_t)row * N + col0] = v;
            } else {
                bf16x4 o;
#pragma unroll
                for (int rr = 0; rr < 4; ++rr) o[rr] = (__bf16)v[rr];
                *(bf16x4*)&C[(size_t)row * N + col0] = o;
            }
        }
    }
}

extern "C" void kernel_launch(void* const* d_in, const int* in_sizes, int n_in,
                              void* d_out, int out_size, void* d_ws, size_t ws_size,
                              hipStream_t stream) {
    const float* x  = (const float*)d_in[0];
    const float* w1 = (const float*)d_in[1];
    const float* b1 = (const float*)d_in[2];
    const float* w2 = (const float*)d_in[3];
    const float* b2 = (const float*)d_in[4];
    const float* w3 = (const float*)d_in[5];
    const float* b3 = (const float*)d_in[6];

    const int total = (out_size - B_CONST) / H_CONST;  // 32896
    float* out = (float*)d_out;
    float* out_pc = out + (size_t)total * H_CONST;

    char* ws = (char*)d_ws;
    int* valid  = (int*)ws;
    int* pc     = valid + 256;
    int* starts = pc + 256;
    int* cum    = starts + 256;
    __bf16* w1t = (__bf16*)(ws + 4096);                        // 1024x32
    __bf16* w2t = w1t + (size_t)H_CONST * 32;                  // 1024x1024
    __bf16* w3t = w2t + (size_t)H_CONST * H_CONST;             // 1024x1024
    __bf16* patches = w3t + (size_t)H_CONST * H_CONST;         // total x 32
    __bf16* h1 = patches + (size_t)total * 32;                 // total x 1024
    __bf16* h2 = h1 + (size_t)total * H_CONST;                 // total x 1024

    k_valid<<<B_CONST, 256, 0, stream>>>(x, valid);
    k_scan<<<1, B_CONST, 0, stream>>>(valid, pc, starts, cum, out_pc);
    k_gather<<<(total * 32 + 255) / 256, 256, 0, stream>>>(x, valid, cum, starts, patches, total);
    k_w1t<<<4, 256, 0, stream>>>(w1, w1t);
    dim3 tg(H_CONST / 32, H_CONST / 32);
    k_transpose_cvt<<<tg, 256, 0, stream>>>(w2, w2t, H_CONST, H_CONST);
    k_transpose_cvt<<<tg, 256, 0, stream>>>(w3, w3t, H_CONST, H_CONST);

    // layer 1: K=32 (R3 kernel)
    dim3 g1(H_CONST / 128, total / 128);   // 8 x 257 = 2056, %8 == 0
    k_mfma_gemm<true, __bf16><<<g1, dim3(256), 0, stream>>>(patches, w1t, b1, h1, total, H_CONST, 32);

    // layers 2/3: ring-3 counted-vmcnt kernel, 3 blocks/CU
    k_gemm_r3<true,  __bf16><<<g1, dim3(256), 0, stream>>>(h1, w2t, b2, h2, total, H_CONST, H_CONST);
    k_gemm_r3<false, float ><<<g1, dim3(256), 0, stream>>>(h2, w3t, b3, out, total, H_CONST, H_CONST);
}

// Round 9
// 240.384 us; speedup vs baseline: 1.2381x; 1.0422x over previous
//
#include <hip/hip_runtime.h>
#include <hip/hip_bf16.h>
#include <math.h>

#define B_CONST 256
#define T_CONST 8192
#define P_CONST 16
#define H_CONST 1024

typedef __bf16 bf16x8 __attribute__((ext_vector_type(8)));
typedef __bf16 bf16x4 __attribute__((ext_vector_type(4)));
typedef float  f32x4  __attribute__((ext_vector_type(4)));
typedef float  f32x16 __attribute__((ext_vector_type(16)));

typedef __attribute__((address_space(3))) void       as3_void;
typedef const __attribute__((address_space(1))) void as1_cvoid;

__device__ __forceinline__ void gload_lds16(const void* g, void* l) {
    __builtin_amdgcn_global_load_lds((as1_cvoid*)g, (as3_void*)l, 16, 0, 0);
}

// fast gelu: x * sigmoid(1.5957691 * x * (1 + 0.044715 x^2))
__device__ __forceinline__ float gelu_fast(float x) {
    float z = 1.5957691216057308f * x * __builtin_fmaf(0.044715f, x * x, 1.0f);
    return x * __builtin_amdgcn_rcpf(1.0f + __expf(-z));
}

// ------------- kernel 1: per-batch valid count via ballot binary search --------
// mask[b,t] = (t < length[b]) is a prefix mask by construction, so valid =
// first zero position. 3 rounds: stride-128 probe (64 lanes), stride-2 probe,
// single probe. Reads ~130 floats/batch instead of 8192 (saves ~67 MB).
__global__ __launch_bounds__(64) void k_valid(const float* __restrict__ x,
                                              int* __restrict__ valid) {
    const int b = blockIdx.x;
    const int l = threadIdx.x;
    const float* m = x + (size_t)b * (T_CONST * 2) + 1;   // mask[t] = m[2t]
    bool one1 = m[(size_t)2 * (l * 128)] > 0.5f;
    int c1 = __popcll(__ballot(one1));
    int v = 0;
    if (c1 > 0) {
        int base = (c1 - 1) * 128;
        bool one2 = m[(size_t)2 * (base + l * 2)] > 0.5f;
        int c2 = __popcll(__ballot(one2));          // >= 1
        int tp = base + 2 * c2 - 1;
        v = (m[(size_t)2 * tp] > 0.5f) ? (base + 2 * c2) : (base + 2 * c2 - 1);
    }
    if (l == 0) valid[b] = v;
}

// ---------------- kernel 2: pc + scan; writes pc (as float) to out tail --------
__global__ void k_scan(const int* __restrict__ valid, int* __restrict__ pc,
                       int* __restrict__ starts, int* __restrict__ cum,
                       float* __restrict__ out_pc) {
    __shared__ int s[B_CONST];
    int t = threadIdx.x;
    int v = valid[t];
    int p = (v + P_CONST - 1) / P_CONST;
    s[t] = p;
    __syncthreads();
    for (int off = 1; off < B_CONST; off <<= 1) {
        int add = (t >= off) ? s[t - off] : 0;
        __syncthreads();
        s[t] += add;
        __syncthreads();
    }
    pc[t] = p;
    cum[t] = s[t];
    starts[t] = s[t] - p;
    out_pc[t] = (float)p;
}

// ---------------- kernel 3: gather patches (total x 32 bf16, K padded) ---------
__global__ void k_gather(const float* __restrict__ x, const int* __restrict__ valid,
                         const int* __restrict__ cum, const int* __restrict__ starts,
                         __bf16* __restrict__ patches, int total) {
    int tid = blockIdx.x * blockDim.x + threadIdx.x;
    if (tid >= total * 32) return;
    int j = tid >> 5, k = tid & 31;
    int lo = 0, hi = B_CONST - 1;
    while (lo < hi) { int mid = (lo + hi) >> 1; if (cum[mid] > j) hi = mid; else lo = mid + 1; }
    int b = lo;
    int p = j - starts[b];
    float v = 0.f;
    if (k < 16) {
        int idx = p * P_CONST + k;
        if (idx < valid[b]) v = x[(size_t)b * (T_CONST * 2) + 2 * idx];
    }
    patches[tid] = (__bf16)v;
}

// ---------------- weight prep: transpose K x N fp32 -> N x K bf16 --------------
__global__ void k_transpose_cvt(const float* __restrict__ W, __bf16* __restrict__ WT,
                                int Kdim, int Ndim) {
    __shared__ float tile[32][33];
    int n0 = blockIdx.x * 32, k0 = blockIdx.y * 32;
    int c = threadIdx.x & 31, r0 = threadIdx.x >> 5;
    for (int r = r0; r < 32; r += 8) tile[r][c] = W[(size_t)(k0 + r) * Ndim + n0 + c];
    __syncthreads();
    for (int r = r0; r < 32; r += 8) WT[(size_t)(n0 + r) * Kdim + k0 + c] = (__bf16)tile[c][r];
}

// w1 is 16 x 1024 -> w1t 1024 x 32 (zero-padded K)
__global__ void k_w1t(const float* __restrict__ w1, __bf16* __restrict__ w1t) {
    int n = blockIdx.x * 256 + threadIdx.x;
    if (n >= H_CONST) return;
    for (int k = 0; k < 32; ++k)
        w1t[n * 32 + k] = (k < 16) ? (__bf16)w1[k * H_CONST + n] : (__bf16)0.f;
}

// ---------------- layer-1 GEMM (K=32): proven R3 128x128 structure -------------
template <bool GELU, typename TOut>
__global__ __launch_bounds__(256) void k_mfma_gemm(
    const __bf16* __restrict__ A, const __bf16* __restrict__ WT,
    const float* __restrict__ bias, TOut* __restrict__ C,
    int M, int N, int K) {
    __shared__ __bf16 As[128][32];
    __shared__ __bf16 Bs[128][32];

    const int lane = threadIdx.x & 63;
    const int wid  = threadIdx.x >> 6;
    const int wr = wid >> 1, wc = wid & 1;

    const int nwg_x = gridDim.x;
    const int orig = blockIdx.y * nwg_x + blockIdx.x;
    const int cpx = (nwg_x * gridDim.y) >> 3;
    const int wgid = (orig & 7) * cpx + (orig >> 3);
    const int brow = (wgid / nwg_x) * 128;
    const int bcol = (wgid % nwg_x) * 128;

    f32x4 acc[4][4];
#pragma unroll
    for (int i = 0; i < 4; ++i)
#pragma unroll
        for (int j = 0; j < 4; ++j)
            acc[i][j] = (f32x4){0.f, 0.f, 0.f, 0.f};

    const int sr = lane >> 2;
    const int sc = (lane & 3) * 8;
    const size_t a_base = (size_t)(brow + wid * 16 + sr) * K + sc;
    const size_t b_base = (size_t)(bcol + wid * 16 + sr) * K + sc;
    const size_t stride64 = (size_t)64 * K;

    const int lr = lane & 15;
    const int lk = (lane >> 4) * 8;

    for (int kt = 0; kt < K; kt += 32) {
        gload_lds16(A  + a_base + kt,            &As[wid * 16][0]);
        gload_lds16(A  + a_base + stride64 + kt, &As[64 + wid * 16][0]);
        gload_lds16(WT + b_base + kt,            &Bs[wid * 16][0]);
        gload_lds16(WT + b_base + stride64 + kt, &Bs[64 + wid * 16][0]);
        __syncthreads();

        bf16x8 af[4], bfr[4];
#pragma unroll
        for (int mf = 0; mf < 4; ++mf)
            af[mf] = *(const bf16x8*)&As[wr * 64 + mf * 16 + lr][lk];
#pragma unroll
        for (int nf = 0; nf < 4; ++nf)
            bfr[nf] = *(const bf16x8*)&Bs[wc * 64 + nf * 16 + lr][lk];
#pragma unroll
        for (int mf = 0; mf < 4; ++mf)
#pragma unroll
            for (int nf = 0; nf < 4; ++nf)
                acc[mf][nf] = __builtin_amdgcn_mfma_f32_16x16x32_bf16(
                    bfr[nf], af[mf], acc[mf][nf], 0, 0, 0);
        __syncthreads();
    }

    const int m_off = lane & 15;
    const int c4 = (lane >> 4) << 2;
#pragma unroll
    for (int nf = 0; nf < 4; ++nf) {
        const int col0 = bcol + wc * 64 + nf * 16 + c4;
        const f32x4 bv = *(const f32x4*)&bias[col0];
#pragma unroll
        for (int mf = 0; mf < 4; ++mf) {
            const int row = brow + wr * 64 + mf * 16 + m_off;
            f32x4 v = acc[mf][nf] + bv;
            if (GELU) {
#pragma unroll
                for (int r = 0; r < 4; ++r) v[r] = gelu_fast(v[r]);
            }
            if constexpr (sizeof(TOut) == 4) {
                *(f32x4*)&C[(size_t)row * N + col0] = v;
            } else {
                bf16x4 o;
#pragma unroll
                for (int r = 0; r < 4; ++r) o[r] = (__bf16)v[r];
                *(bf16x4*)&C[(size_t)row * N + col0] = o;
            }
        }
    }
}

// ---------------- big GEMM: R6 schedule + mfma_f32_32x32x16_bf16 ---------------
// Identical skeleton to R6's k_gemm_sb (128x128 tile, 4 waves 2x2, BK=64,
// 32 KiB single buffer, 3 blocks/CU, 2 barriers/tile, proven 0-conflict XOR
// swizzle), but the per-wave 64x64 is computed as 2x2 of 32x32x16 MFMA:
// +14% MFMA pipe throughput (2495 vs 2176 TF ubench), half the MFMA instrs.
// Operand layout (m74/m101 HW-verified, swapped operands -> C^T frag):
//   lane supplies row l&31, k-half (l>>5)*8 of its operand matrix;
//   output: C-row = l&31 (+offsets), C-cols = (r&3)+8*(r>>2)+4*(l>>5).
template <bool GELU, typename TOut>
__global__ __launch_bounds__(256, 3) void k_gemm_sb32(
    const __bf16* __restrict__ A, const __bf16* __restrict__ WT,
    const float* __restrict__ bias, TOut* __restrict__ C,
    int M, int N, int K) {
    __shared__ __bf16 As[128][64];   // 16 KiB
    __shared__ __bf16 Bs[128][64];   // 16 KiB

    const int lane = threadIdx.x & 63;
    const int wid  = threadIdx.x >> 6;
    const int wr = wid >> 1, wc = wid & 1;

    const int nwg_x = gridDim.x;
    const int orig = blockIdx.y * nwg_x + blockIdx.x;
    const int cpx = (nwg_x * gridDim.y) >> 3;   // nwg = 2056, %8 == 0
    const int wgid = (orig & 7) * cpx + (orig >> 3);
    const int brow = (wgid / nwg_x) * 128;
    const int bcol = (wgid % nwg_x) * 128;

    f32x16 acc[2][2];
#pragma unroll
    for (int i = 0; i < 2; ++i)
#pragma unroll
        for (int j = 0; j < 2; ++j)
#pragma unroll
            for (int e = 0; e < 16; ++e)
                acc[i][j][e] = 0.f;

    // staging identical to R6: per wave 32 rows of A + 32 rows of B, 8-row
    // chunks, pre-swizzled global source (LDS[row][8j..] = global col-group
    // j ^ (row&7)).
    const int lr8 = lane >> 3;                       // 0..7
    const int swz = 8 * ((lane & 7) ^ lr8);
    const __bf16* Ab = A  + (size_t)(brow + wid * 32 + lr8) * K + swz;
    const __bf16* Bb = WT + (size_t)(bcol + wid * 32 + lr8) * K + swz;
    const size_t rs8 = (size_t)8 * K;

#define STG(kt)                                                        \
    do {                                                               \
        gload_lds16(Ab + (kt),           &As[wid * 32][0]);            \
        gload_lds16(Ab + rs8 + (kt),     &As[wid * 32 + 8][0]);        \
        gload_lds16(Ab + 2 * rs8 + (kt), &As[wid * 32 + 16][0]);       \
        gload_lds16(Ab + 3 * rs8 + (kt), &As[wid * 32 + 24][0]);       \
        gload_lds16(Bb + (kt),           &Bs[wid * 32][0]);            \
        gload_lds16(Bb + rs8 + (kt),     &Bs[wid * 32 + 8][0]);        \
        gload_lds16(Bb + 2 * rs8 + (kt), &Bs[wid * 32 + 16][0]);       \
        gload_lds16(Bb + 3 * rs8 + (kt), &Bs[wid * 32 + 24][0]);       \
    } while (0)

    // fragment-read addressing: operand row = {wr|wc}*64 + f*32 + (lane&31);
    // byte col = kk*32 + (lane>>5)*16, XOR-swizzled with (row&7)<<4 = (lane&7)<<4.
    const int l31  = lane & 31;
    const int kh16 = (lane >> 5) * 16;
    const int rswz = (lane & 7) << 4;

    const int nt = K >> 6;
    STG(0);

    for (int t = 0; t < nt; ++t) {
        __syncthreads();                 // stage-t loads landed (vmcnt drain)

        const char* ab = (const char*)&As[0][0];
        const char* bb = (const char*)&Bs[0][0];
        bf16x8 af[4][2], bfr[4][2];
#pragma unroll
        for (int kk = 0; kk < 4; ++kk) {
            const int cb = (kk * 32 + kh16) ^ rswz;
#pragma unroll
            for (int mf = 0; mf < 2; ++mf)
                af[kk][mf] = *(const bf16x8*)(ab + (wr * 64 + mf * 32 + l31) * 128 + cb);
#pragma unroll
            for (int nf = 0; nf < 2; ++nf)
                bfr[kk][nf] = *(const bf16x8*)(bb + (wc * 64 + nf * 32 + l31) * 128 + cb);
        }
        __syncthreads();                 // all waves done reading LDS (cheap)

        if (t + 1 < nt) STG((t + 1) << 6);   // next tile flies under the MFMAs

        __builtin_amdgcn_s_setprio(1);
#pragma unroll
        for (int kk = 0; kk < 4; ++kk)
#pragma unroll
            for (int mf = 0; mf < 2; ++mf)
#pragma unroll
                for (int nf = 0; nf < 2; ++nf)
                    acc[mf][nf] = __builtin_amdgcn_mfma_f32_32x32x16_bf16(
                        bfr[kk][nf], af[kk][mf], acc[mf][nf], 0, 0, 0);
        __builtin_amdgcn_s_setprio(0);
    }
#undef STG

    // epilogue: C^T frag -> lane l owns C-row l&31 (+offsets); cols come in
    // four groups of 4 consecutive: regs 4q..4q+3 -> cols q*8 + 4*(l>>5) + 0..3.
    const int kh4 = (lane >> 5) * 4;
#pragma unroll
    for (int nf = 0; nf < 2; ++nf) {
#pragma unroll
        for (int mf = 0; mf < 2; ++mf) {
            const int row = brow + wr * 64 + mf * 32 + l31;
#pragma unroll
            for (int q = 0; q < 4; ++q) {
                const int col0 = bcol + wc * 64 + nf * 32 + q * 8 + kh4;
                const f32x4 bv = *(const f32x4*)&bias[col0];
                f32x4 v;
#pragma unroll
                for (int e = 0; e < 4; ++e) v[e] = acc[mf][nf][q * 4 + e];
                v += bv;
                if (GELU) {
#pragma unroll
                    for (int e = 0; e < 4; ++e) v[e] = gelu_fast(v[e]);
                }
                if constexpr (sizeof(TOut) == 4) {
                    *(f32x4*)&C[(size_t)row * N + col0] = v;
                } else {
                    bf16x4 o;
#pragma unroll
                    for (int e = 0; e < 4; ++e) o[e] = (__bf16)v[e];
                    *(bf16x4*)&C[(size_t)row * N + col0] = o;
                }
            }
        }
    }
}

extern "C" void kernel_launch(void* const* d_in, const int* in_sizes, int n_in,
                              void* d_out, int out_size, void* d_ws, size_t ws_size,
                              hipStream_t stream) {
    const float* x  = (const float*)d_in[0];
    const float* w1 = (const float*)d_in[1];
    const float* b1 = (const float*)d_in[2];
    const float* w2 = (const float*)d_in[3];
    const float* b2 = (const float*)d_in[4];
    const float* w3 = (const float*)d_in[5];
    const float* b3 = (const float*)d_in[6];

    const int total = (out_size - B_CONST) / H_CONST;  // 32896
    float* out = (float*)d_out;
    float* out_pc = out + (size_t)total * H_CONST;

    char* ws = (char*)d_ws;
    int* valid  = (int*)ws;
    int* pc     = valid + 256;
    int* starts = pc + 256;
    int* cum    = starts + 256;
    __bf16* w1t = (__bf16*)(ws + 4096);                        // 1024x32
    __bf16* w2t = w1t + (size_t)H_CONST * 32;                  // 1024x1024
    __bf16* w3t = w2t + (size_t)H_CONST * H_CONST;             // 1024x1024
    __bf16* patches = w3t + (size_t)H_CONST * H_CONST;         // total x 32
    __bf16* h1 = patches + (size_t)total * 32;                 // total x 1024
    __bf16* h2 = h1 + (size_t)total * H_CONST;                 // total x 1024

    k_valid<<<B_CONST, 64, 0, stream>>>(x, valid);
    k_scan<<<1, B_CONST, 0, stream>>>(valid, pc, starts, cum, out_pc);
    k_gather<<<(total * 32 + 255) / 256, 256, 0, stream>>>(x, valid, cum, starts, patches, total);
    k_w1t<<<4, 256, 0, stream>>>(w1, w1t);
    dim3 tg(H_CONST / 32, H_CONST / 32);
    k_transpose_cvt<<<tg, 256, 0, stream>>>(w2, w2t, H_CONST, H_CONST);
    k_transpose_cvt<<<tg, 256, 0, stream>>>(w3, w3t, H_CONST, H_CONST);

    // layer 1: K=32 (R3 kernel)
    dim3 g1(H_CONST / 128, total / 128);   // 8 x 257 = 2056, %8 == 0
    k_mfma_gemm<true, __bf16><<<g1, dim3(256), 0, stream>>>(patches, w1t, b1, h1, total, H_CONST, 32);

    // layers 2/3: R6 schedule with 32x32x16 MFMA
    k_gemm_sb32<true,  __bf16><<<g1, dim3(256), 0, stream>>>(h1, w2t, b2, h2, total, H_CONST, H_CONST);
    k_gemm_sb32<false, float ><<<g1, dim3(256), 0, stream>>>(h2, w3t, b3, out, total, H_CONST, H_CONST);
}

// Round 10
// 210.143 us; speedup vs baseline: 1.4163x; 1.1439x over previous
//
#include <hip/hip_runtime.h>
#include <hip/hip_bf16.h>
#include <math.h>

#define B_CONST 256
#define T_CONST 8192
#define P_CONST 16
#define H_CONST 1024

typedef __bf16 bf16x8 __attribute__((ext_vector_type(8)));
typedef __bf16 bf16x4 __attribute__((ext_vector_type(4)));
typedef float  f32x4  __attribute__((ext_vector_type(4)));

typedef __attribute__((address_space(3))) void       as3_void;
typedef const __attribute__((address_space(1))) void as1_cvoid;

__device__ __forceinline__ void gload_lds16(const void* g, void* l) {
    __builtin_amdgcn_global_load_lds((as1_cvoid*)g, (as3_void*)l, 16, 0, 0);
}

// fast gelu: x * sigmoid(1.5957691 * x * (1 + 0.044715 x^2))
__device__ __forceinline__ float gelu_fast(float x) {
    float z = 1.5957691216057308f * x * __builtin_fmaf(0.044715f, x * x, 1.0f);
    return x * __builtin_amdgcn_rcpf(1.0f + __expf(-z));
}

// ------------- kernel 1: per-batch valid count via ballot binary search --------
// mask[b,t] = (t < length[b]) is a prefix mask, so valid = first zero.
// 3 rounds: stride-128 ballot, stride-2 ballot, single probe.
__global__ __launch_bounds__(64) void k_valid(const float* __restrict__ x,
                                              int* __restrict__ valid) {
    const int b = blockIdx.x;
    const int l = threadIdx.x;
    const float* m = x + (size_t)b * (T_CONST * 2) + 1;   // mask[t] = m[2t]
    bool one1 = m[(size_t)2 * (l * 128)] > 0.5f;
    int c1 = __popcll(__ballot(one1));
    int v = 0;
    if (c1 > 0) {
        int base = (c1 - 1) * 128;
        bool one2 = m[(size_t)2 * (base + l * 2)] > 0.5f;
        int c2 = __popcll(__ballot(one2));          // >= 1
        int tp = base + 2 * c2 - 1;
        v = (m[(size_t)2 * tp] > 0.5f) ? (base + 2 * c2) : (base + 2 * c2 - 1);
    }
    if (l == 0) valid[b] = v;
}

// ---------------- kernel 2: pc + scan; writes pc (as float) to out tail --------
__global__ void k_scan(const int* __restrict__ valid, int* __restrict__ pc,
                       int* __restrict__ starts, int* __restrict__ cum,
                       float* __restrict__ out_pc) {
    __shared__ int s[B_CONST];
    int t = threadIdx.x;
    int v = valid[t];
    int p = (v + P_CONST - 1) / P_CONST;
    s[t] = p;
    __syncthreads();
    for (int off = 1; off < B_CONST; off <<= 1) {
        int add = (t >= off) ? s[t - off] : 0;
        __syncthreads();
        s[t] += add;
        __syncthreads();
    }
    pc[t] = p;
    cum[t] = s[t];
    starts[t] = s[t] - p;
    out_pc[t] = (float)p;
}

// ---------------- weight prep: transpose K x N fp32 -> N x K bf16 --------------
__global__ void k_transpose_cvt(const float* __restrict__ W, __bf16* __restrict__ WT,
                                int Kdim, int Ndim) {
    __shared__ float tile[32][33];
    int n0 = blockIdx.x * 32, k0 = blockIdx.y * 32;
    int c = threadIdx.x & 31, r0 = threadIdx.x >> 5;
    for (int r = r0; r < 32; r += 8) tile[r][c] = W[(size_t)(k0 + r) * Ndim + n0 + c];
    __syncthreads();
    for (int r = r0; r < 32; r += 8) WT[(size_t)(n0 + r) * Kdim + k0 + c] = (__bf16)tile[c][r];
}

// w1 is 16 x 1024 -> w1t 1024 x 32 (zero-padded K)
__global__ void k_w1t(const float* __restrict__ w1, __bf16* __restrict__ w1t) {
    int n = blockIdx.x * 256 + threadIdx.x;
    if (n >= H_CONST) return;
    for (int k = 0; k < 32; ++k)
        w1t[n * 32 + k] = (k < 16) ? (__bf16)w1[k * H_CONST + n] : (__bf16)0.f;
}

// ---------------- layer-1 fused gather+GEMM (K=32, R3 MFMA structure) ----------
// A-tile (128 patches x 32) computed in-register from x (binary search + masked
// float4 loads) and ds_written; B staged via gload_lds from w1t. Single K-iter.
__global__ __launch_bounds__(256) void k_l1_fused(
    const float* __restrict__ x, const int* __restrict__ valid,
    const int* __restrict__ cum, const int* __restrict__ starts,
    const __bf16* __restrict__ w1t, const float* __restrict__ bias,
    __bf16* __restrict__ C, int total) {
    __shared__ __bf16 As[128][32];
    __shared__ __bf16 Bs[128][32];

    const int lane = threadIdx.x & 63;
    const int wid  = threadIdx.x >> 6;
    const int wr = wid >> 1, wc = wid & 1;

    const int nwg_x = gridDim.x;
    const int orig = blockIdx.y * nwg_x + blockIdx.x;
    const int cpx = (nwg_x * gridDim.y) >> 3;
    const int wgid = (orig & 7) * cpx + (orig >> 3);
    const int brow = (wgid / nwg_x) * 128;
    const int bcol = (wgid % nwg_x) * 128;

    // stage B (w1t rows bcol..bcol+127, all 32 cols): 2 loads per wave
    const int sr = lane >> 2;
    const int sc = (lane & 3) * 8;
    const size_t b_base = (size_t)(bcol + wid * 16 + sr) * 32 + sc;
    gload_lds16(w1t + b_base,           &Bs[wid * 16][0]);
    gload_lds16(w1t + b_base + 64 * 32, &Bs[64 + wid * 16][0]);

    // compute A on the fly: thread t -> patch row t>>1, col-half t&1
    {
        const int r  = threadIdx.x >> 1;
        const int ch = threadIdx.x & 1;
        const int j  = brow + r;                 // patch index (< total by grid)
        int lo = 0, hi = B_CONST - 1;
        while (lo < hi) { int mid = (lo + hi) >> 1; if (cum[mid] > j) hi = mid; else lo = mid + 1; }
        const int b = lo;
        const int p = j - starts[b];
        __bf16 vals[16];
        if (ch == 0) {
            const int vb = valid[b];
            const float* xb = x + (size_t)b * (T_CONST * 2) + 32 * p;
#pragma unroll
            for (int i = 0; i < 8; ++i) {
                float4 v = *(const float4*)(xb + 4 * i);
                int i0 = p * 16 + 2 * i;
                vals[2 * i]     = (__bf16)((i0 < vb)     ? v.x : 0.f);
                vals[2 * i + 1] = (__bf16)((i0 + 1 < vb) ? v.z : 0.f);
            }
        } else {
#pragma unroll
            for (int i = 0; i < 16; ++i) vals[i] = (__bf16)0.f;
        }
        *(bf16x8*)&As[r][ch * 16]     = *(bf16x8*)&vals[0];
        *(bf16x8*)&As[r][ch * 16 + 8] = *(bf16x8*)&vals[8];
    }
    __syncthreads();   // drains gload_lds (vmcnt) and ds_writes (lgkm)

    const int lr = lane & 15;
    const int lk = (lane >> 4) * 8;

    f32x4 acc[4][4];
#pragma unroll
    for (int i = 0; i < 4; ++i)
#pragma unroll
        for (int j = 0; j < 4; ++j)
            acc[i][j] = (f32x4){0.f, 0.f, 0.f, 0.f};

    bf16x8 af[4], bfr[4];
#pragma unroll
    for (int mf = 0; mf < 4; ++mf)
        af[mf] = *(const bf16x8*)&As[wr * 64 + mf * 16 + lr][lk];
#pragma unroll
    for (int nf = 0; nf < 4; ++nf)
        bfr[nf] = *(const bf16x8*)&Bs[wc * 64 + nf * 16 + lr][lk];
#pragma unroll
    for (int mf = 0; mf < 4; ++mf)
#pragma unroll
        for (int nf = 0; nf < 4; ++nf)
            acc[mf][nf] = __builtin_amdgcn_mfma_f32_16x16x32_bf16(
                bfr[nf], af[mf], acc[mf][nf], 0, 0, 0);

    // epilogue: swapped C^T frag -> lane holds 4 consecutive cols of one row
    const int c4 = (lane >> 4) << 2;
#pragma unroll
    for (int nf = 0; nf < 4; ++nf) {
        const int col0 = bcol + wc * 64 + nf * 16 + c4;
        const f32x4 bv = *(const f32x4*)&bias[col0];
#pragma unroll
        for (int mf = 0; mf < 4; ++mf) {
            const int row = brow + wr * 64 + mf * 16 + lr;
            f32x4 v = acc[mf][nf] + bv;
#pragma unroll
            for (int rr = 0; rr < 4; ++rr) v[rr] = gelu_fast(v[rr]);
            bf16x4 o;
#pragma unroll
            for (int rr = 0; rr < 4; ++rr) o[rr] = (__bf16)v[rr];
            *(bf16x4*)&C[(size_t)row * H_CONST + col0] = o;
        }
    }
}

// ---------------- big GEMM: single-buffer BK=64, reg-fragment pipelining -------
// R6 proven kernel (86 us, 802 TF, 0 bank conflicts): 128x128 tile, 4 waves
// (2x2, 64x64 each), BK=64, 32 KiB single LDS buffer -> 3 blocks/CU.
// Per K-tile: sync(stage-t landed) -> read ALL 16 b128 frags to regs ->
// sync(block-wide reads done) -> issue STG(t+1) into SAME buffer -> 32 MFMA
// overlap the staging loads' flight. XOR swizzle both-sides (rule 21).
template <bool GELU, typename TOut>
__global__ __launch_bounds__(256, 3) void k_gemm_sb(
    const __bf16* __restrict__ A, const __bf16* __restrict__ WT,
    const float* __restrict__ bias, TOut* __restrict__ C,
    int M, int N, int K) {
    __shared__ __bf16 As[128][64];   // 16 KiB
    __shared__ __bf16 Bs[128][64];   // 16 KiB

    const int lane = threadIdx.x & 63;
    const int wid  = threadIdx.x >> 6;
    const int wr = wid >> 1, wc = wid & 1;

    const int nwg_x = gridDim.x;
    const int orig = blockIdx.y * nwg_x + blockIdx.x;
    const int cpx = (nwg_x * gridDim.y) >> 3;   // nwg = 2056, %8 == 0
    const int wgid = (orig & 7) * cpx + (orig >> 3);
    const int brow = (wgid / nwg_x) * 128;
    const int bcol = (wgid % nwg_x) * 128;

    f32x4 acc[4][4];
#pragma unroll
    for (int i = 0; i < 4; ++i)
#pragma unroll
        for (int j = 0; j < 4; ++j)
            acc[i][j] = (f32x4){0.f, 0.f, 0.f, 0.f};

    // staging: per wave 32 rows of A + 32 rows of B per K-tile, 8-row chunks.
    // global source pre-swizzled: LDS[row][8j..8j+7] holds global col-group
    // j ^ (row&7).
    const int lr8 = lane >> 3;                       // 0..7
    const int swz = 8 * ((lane & 7) ^ lr8);
    const __bf16* Ab = A  + (size_t)(brow + wid * 32 + lr8) * K + swz;
    const __bf16* Bb = WT + (size_t)(bcol + wid * 32 + lr8) * K + swz;
    const size_t rs8 = (size_t)8 * K;

#define STG(kt)                                                        \
    do {                                                               \
        gload_lds16(Ab + (kt),           &As[wid * 32][0]);            \
        gload_lds16(Ab + rs8 + (kt),     &As[wid * 32 + 8][0]);        \
        gload_lds16(Ab + 2 * rs8 + (kt), &As[wid * 32 + 16][0]);       \
        gload_lds16(Ab + 3 * rs8 + (kt), &As[wid * 32 + 24][0]);       \
        gload_lds16(Bb + (kt),           &Bs[wid * 32][0]);            \
        gload_lds16(Bb + rs8 + (kt),     &Bs[wid * 32 + 8][0]);        \
        gload_lds16(Bb + 2 * rs8 + (kt), &Bs[wid * 32 + 16][0]);       \
        gload_lds16(Bb + 3 * rs8 + (kt), &Bs[wid * 32 + 24][0]);       \
    } while (0)

    // fragment-read addressing (swizzled)
    const int lr   = lane & 15;
    const int hi16 = (lane >> 4) * 16;   // byte offset of k-subgroup within half
    const int rswz = (lane & 7) << 4;    // (row&7)<<4

    const int nt = K >> 6;
    STG(0);

    for (int t = 0; t < nt; ++t) {
        __syncthreads();                 // stage-t loads landed (vmcnt drain)

        const char* ab = (const char*)&As[0][0];
        const char* bb = (const char*)&Bs[0][0];
        bf16x8 af[2][4], bfr[2][4];
#pragma unroll
        for (int kk = 0; kk < 2; ++kk) {
            const int cb = (kk * 64 + hi16) ^ rswz;
#pragma unroll
            for (int mf = 0; mf < 4; ++mf)
                af[kk][mf] = *(const bf16x8*)(ab + (wr * 64 + mf * 16 + lr) * 128 + cb);
#pragma unroll
            for (int nf = 0; nf < 4; ++nf)
                bfr[kk][nf] = *(const bf16x8*)(bb + (wc * 64 + nf * 16 + lr) * 128 + cb);
        }
        __syncthreads();                 // all waves done reading LDS (cheap)

        if (t + 1 < nt) STG((t + 1) << 6);   // next tile flies under the MFMAs

        __builtin_amdgcn_s_setprio(1);
#pragma unroll
        for (int kk = 0; kk < 2; ++kk)
#pragma unroll
            for (int mf = 0; mf < 4; ++mf)
#pragma unroll
                for (int nf = 0; nf < 4; ++nf)
                    acc[mf][nf] = __builtin_amdgcn_mfma_f32_16x16x32_bf16(
                        bfr[kk][nf], af[kk][mf], acc[mf][nf], 0, 0, 0);
        __builtin_amdgcn_s_setprio(0);
    }
#undef STG

    // epilogue: swapped C^T frag -> lane holds 4 consecutive cols of one row
    const int c4 = (lane >> 4) << 2;
#pragma unroll
    for (int nf = 0; nf < 4; ++nf) {
        const int col0 = bcol + wc * 64 + nf * 16 + c4;
        const f32x4 bv = *(const f32x4*)&bias[col0];
#pragma unroll
        for (int mf = 0; mf < 4; ++mf) {
            const int row = brow + wr * 64 + mf * 16 + lr;
            f32x4 v = acc[mf][nf] + bv;
            if (GELU) {
#pragma unroll
                for (int rr = 0; rr < 4; ++rr) v[rr] = gelu_fast(v[rr]);
            }
            if constexpr (sizeof(TOut) == 4) {
                *(f32x4*)&C[(size_t)row * N + col0] = v;
            } else {
                bf16x4 o;
#pragma unroll
                for (int rr = 0; rr < 4; ++rr) o[rr] = (__bf16)v[rr];
                *(bf16x4*)&C[(size_t)row * N + col0] = o;
            }
        }
    }
}

extern "C" void kernel_launch(void* const* d_in, const int* in_sizes, int n_in,
                              void* d_out, int out_size, void* d_ws, size_t ws_size,
                              hipStream_t stream) {
    const float* x  = (const float*)d_in[0];
    const float* w1 = (const float*)d_in[1];
    const float* b1 = (const float*)d_in[2];
    const float* w2 = (const float*)d_in[3];
    const float* b2 = (const float*)d_in[4];
    const float* w3 = (const float*)d_in[5];
    const float* b3 = (const float*)d_in[6];

    const int total = (out_size - B_CONST) / H_CONST;  // 32896
    float* out = (float*)d_out;
    float* out_pc = out + (size_t)total * H_CONST;

    char* ws = (char*)d_ws;
    int* valid  = (int*)ws;
    int* pc     = valid + 256;
    int* starts = pc + 256;
    int* cum    = starts + 256;
    __bf16* w1t = (__bf16*)(ws + 4096);                        // 1024x32
    __bf16* w2t = w1t + (size_t)H_CONST * 32;                  // 1024x1024
    __bf16* w3t = w2t + (size_t)H_CONST * H_CONST;             // 1024x1024
    __bf16* h1 = w3t + (size_t)H_CONST * H_CONST;              // total x 1024
    __bf16* h2 = h1 + (size_t)total * H_CONST;                 // total x 1024

    k_valid<<<B_CONST, 64, 0, stream>>>(x, valid);
    k_scan<<<1, B_CONST, 0, stream>>>(valid, pc, starts, cum, out_pc);
    k_w1t<<<4, 256, 0, stream>>>(w1, w1t);
    dim3 tg(H_CONST / 32, H_CONST / 32);
    k_transpose_cvt<<<tg, 256, 0, stream>>>(w2, w2t, H_CONST, H_CONST);
    k_transpose_cvt<<<tg, 256, 0, stream>>>(w3, w3t, H_CONST, H_CONST);

    // layer 1: fused gather + K=32 GEMM
    dim3 g1(H_CONST / 128, total / 128);   // 8 x 257 = 2056, %8 == 0
    k_l1_fused<<<g1, dim3(256), 0, stream>>>(x, valid, cum, starts, w1t, b1, h1, total);

    // layers 2/3: R6 single-buffer BK=64 pipelined kernel, 3 blocks/CU
    k_gemm_sb<true,  __bf16><<<g1, dim3(256), 0, stream>>>(h1, w2t, b2, h2, total, H_CONST, H_CONST);
    k_gemm_sb<false, float ><<<g1, dim3(256), 0, stream>>>(h2, w3t, b3, out, total, H_CONST, H_CONST);
}